// Round 14
// baseline (385.022 us; speedup 1.0000x reference)
//
#include <hip/hip_runtime.h>
#include <hip/hip_fp16.h>
#include <math.h>

#define N_NODES 100000
#define NC 391               // ceil(N_NODES/256) coarse buckets (256 nodes each)
#define NBLK64 1563          // ceil(N_NODES/64)
#define BN_EPS 1e-5f
#define PART_BLOCKS 128

typedef _Float16 half4v __attribute__((ext_vector_type(4)));
typedef float f32x4 __attribute__((ext_vector_type(4)));

// packed fp16 max(x, 0) via v_pk_max_f16 (no __hmax2 in this ROCm's headers)
static __device__ __forceinline__ __half2 h2relu(__half2 a) {
    unsigned int r, x = *reinterpret_cast<unsigned int*>(&a);
    asm volatile("v_pk_max_f16 %0, %1, %2" : "=v"(r) : "v"(x), "v"(0u));
    return *reinterpret_cast<__half2*>(&r);
}

// ---------------------------------------------------------------------------
__global__ void zero_misc_k(float* stats, int* gcnt) {
    int gid = blockIdx.x * blockDim.x + threadIdx.x;
    if (gid < 384) stats[gid] = 0.f;
    if (gid < NC) gcnt[gid] = 0;
}

// x fp32 -> fp16 (4 elems per thread)
__global__ void tofp16_k(const float* __restrict__ x, __half* __restrict__ xh, int n4) {
    int gid = blockIdx.x * blockDim.x + threadIdx.x;
    if (gid >= n4) return;
    float4 v = reinterpret_cast<const float4*>(x)[gid];
    union { float2 f; __half2 h[2]; } u;
    u.h[0] = __float22half2_rn(make_float2(v.x, v.y));
    u.h[1] = __float22half2_rn(make_float2(v.z, v.w));
    reinterpret_cast<float2*>(xh)[gid] = u.f;
}

// transpose + fp16-convert the six 64x64 MLP weights: Wt[c][k] = fp16(W[k][c])
__global__ void wtr_k(const float* w0, const float* w1, const float* w2,
                      const float* w3, const float* w4, const float* w5,
                      _Float16* wth) {
    const float* src[6] = {w0, w1, w2, w3, w4, w5};
    const float* W = src[blockIdx.x];
    _Float16* D = wth + (size_t)blockIdx.x * 4096;
    for (int idx = threadIdx.x; idx < 4096; idx += 256) {
        int k = idx >> 6, c = idx & 63;
        D[c * 64 + k] = (_Float16)W[idx];
    }
}

// coarse histogram: bucket = dst >> 8
__global__ __launch_bounds__(256) void histC_k(const int* __restrict__ ei,
                                               int* __restrict__ gcnt, int E) {
    __shared__ int cnt[NC];
    for (int i = threadIdx.x; i < NC; i += 256) cnt[i] = 0;
    __syncthreads();
    int per = (E + gridDim.x - 1) / gridDim.x;
    int s0 = blockIdx.x * per, s1 = min(E, s0 + per);
    for (int e = s0 + threadIdx.x; e < s1; e += 256)
        atomicAdd(&cnt[ei[E + e] >> 8], 1);
    __syncthreads();
    for (int i = threadIdx.x; i < NC; i += 256)
        if (cnt[i]) atomicAdd(&gcnt[i], cnt[i]);
}

// exclusive scan of NC coarse counts (single block, 2 elems/thread)
__global__ __launch_bounds__(256) void scanC_k(const int* __restrict__ gcnt,
                                               int* __restrict__ cbase,
                                               int* __restrict__ gcursor) {
    __shared__ int tmp[256];
    int t = threadIdx.x;
    int v0 = (2 * t < NC) ? gcnt[2 * t] : 0;
    int v1 = (2 * t + 1 < NC) ? gcnt[2 * t + 1] : 0;
    int s = v0 + v1;
    tmp[t] = s;
    __syncthreads();
    for (int off = 1; off < 256; off <<= 1) {
        int a = (t >= off) ? tmp[t - off] : 0;
        __syncthreads();
        tmp[t] += a;
        __syncthreads();
    }
    int run = tmp[t] - s;
    if (2 * t < NC) { cbase[2 * t] = run; gcursor[2 * t] = run; }
    run += v0;
    if (2 * t + 1 < NC) { cbase[2 * t + 1] = run; gcursor[2 * t + 1] = run; }
    if (t == 255) cbase[NC] = tmp[255];  // == E
}

// coarse partition: part[] entries = (dst&255)<<17 | src, coarse-contiguous.
__global__ __launch_bounds__(256) void partC_k(const int* __restrict__ ei,
                                               int* __restrict__ gcursor,
                                               int* __restrict__ part, int E) {
    __shared__ int cnt[NC];
    __shared__ int base[NC];
    for (int i = threadIdx.x; i < NC; i += 256) cnt[i] = 0;
    __syncthreads();
    int per = (E + gridDim.x - 1) / gridDim.x;
    int s0 = blockIdx.x * per, s1 = min(E, s0 + per);
    for (int e = s0 + threadIdx.x; e < s1; e += 256)
        atomicAdd(&cnt[ei[E + e] >> 8], 1);
    __syncthreads();
    for (int i = threadIdx.x; i < NC; i += 256) {
        int c = cnt[i];
        base[i] = c ? atomicAdd(&gcursor[i], c) : 0;
    }
    __syncthreads();
    for (int i = threadIdx.x; i < NC; i += 256) cnt[i] = 0;
    __syncthreads();
    for (int e = s0 + threadIdx.x; e < s1; e += 256) {
        int s = ei[e], d = ei[E + e];
        int b = d >> 8, dl = d & 255;
        int lo = atomicAdd(&cnt[b], 1);
        part[base[b] + lo] = (dl << 17) | s;
    }
}

// per-coarse-bucket counting sort -> row_ptr + node-ordered csr_src.
__global__ __launch_bounds__(256) void csrD_k(const int* __restrict__ part,
                                              const int* __restrict__ cbase,
                                              int* __restrict__ row_ptr,
                                              int* __restrict__ csr_src) {
    __shared__ int cnt[256];
    __shared__ int tmp[256];
    __shared__ int cur[256];
    int b = blockIdx.x;
    int t = threadIdx.x;
    int e0 = cbase[b], e1 = cbase[b + 1];
    cnt[t] = 0;
    __syncthreads();
    for (int i = e0 + t; i < e1; i += 256) atomicAdd(&cnt[(part[i] >> 17) & 255], 1);
    __syncthreads();
    int c = cnt[t];
    tmp[t] = c;
    __syncthreads();
    for (int off = 1; off < 256; off <<= 1) {
        int a = (t >= off) ? tmp[t - off] : 0;
        __syncthreads();
        tmp[t] += a;
        __syncthreads();
    }
    int excl = tmp[t] - c;
    int node = b * 256 + t;
    if (node < N_NODES) row_ptr[node] = e0 + excl;
    cur[t] = e0 + excl;
    __syncthreads();
    for (int i = e0 + t; i < e1; i += 256) {
        int u = part[i];
        int dl = (u >> 17) & 255;
        int pos = atomicAdd(&cur[dl], 1);
        csr_src[pos] = u & 0x1FFFF;
    }
    if (b == NC - 1 && t == 0) row_ptr[N_NODES] = cbase[NC];
}

// ---------------------------------------------------------------------------
// Fused GIN layer: block = 64 nodes, 256 threads, ~9.7 KB LDS.
// Phase A: register gather with fused BN+ReLU of the PREVIOUS layer (packed
//          fp16 hfma2 + v_pk_max_f16 on load; identity when FIRST) -> xs.
// Phase B: MFMA MLP (v_mfma_f32_16x16x16_f16), h1 per-wave in xs; store RAW h
//          + BN stats for this layer.
template <bool FIRST>
__global__ __launch_bounds__(256) void layer_k(
    const __half* __restrict__ hin,
    const float* __restrict__ pstats, const float* __restrict__ pg,
    const float* __restrict__ pbt,
    const int* __restrict__ row_ptr, const int* __restrict__ csr_src,
    const float* __restrict__ epsp,
    const _Float16* __restrict__ wt1, const float* __restrict__ b1,
    const _Float16* __restrict__ wt2, const float* __restrict__ b2,
    __half* __restrict__ hout, float* __restrict__ stats) {
    __shared__ _Float16 xs[64][72];     // row-major gathered tile / h1 / h buffer
    __shared__ float sred[128];

    int tid = threadIdx.x;
    int r0 = blockIdx.x * 64;
    if (tid < 128) sred[tid] = 0.f;

    float eps1 = 1.0f + *epsp;
    int cg = tid & 15, lg = tid >> 4;
    union F2H { float2 f; __half2 h[2]; };

    // per-lane BN(prev) scale/offset for channels cg*4..cg*4+3, packed half2
    __half2 sc01, sc23, of01, of23;
    if (!FIRST) {
        float4 sm = *reinterpret_cast<const float4*>(&pstats[cg * 4]);
        float4 sq = *reinterpret_cast<const float4*>(&pstats[64 + cg * 4]);
        float4 gg = *reinterpret_cast<const float4*>(&pg[cg * 4]);
        float4 bb = *reinterpret_cast<const float4*>(&pbt[cg * 4]);
        const float inv = 1.f / N_NODES;
        float m0 = sm.x * inv, m1 = sm.y * inv, m2 = sm.z * inv, m3 = sm.w * inv;
        float s0 = gg.x * rsqrtf(sq.x * inv - m0 * m0 + BN_EPS);
        float s1 = gg.y * rsqrtf(sq.y * inv - m1 * m1 + BN_EPS);
        float s2 = gg.z * rsqrtf(sq.z * inv - m2 * m2 + BN_EPS);
        float s3 = gg.w * rsqrtf(sq.w * inv - m3 * m3 + BN_EPS);
        sc01 = __floats2half2_rn(s0, s1);
        sc23 = __floats2half2_rn(s2, s3);
        of01 = __floats2half2_rn(bb.x - m0 * s0, bb.y - m1 * s1);
        of23 = __floats2half2_rn(bb.z - m2 * s2, bb.w - m3 * s3);
    }

#define BNH(u)                                               \
    if (!FIRST) {                                            \
        u.h[0] = h2relu(__hfma2(u.h[0], sc01, of01));        \
        u.h[1] = h2relu(__hfma2(u.h[1], sc23, of23));        \
    }

    // ---- Phase A: gather, 16 lanes/node, 4 node-passes ----
#pragma unroll
    for (int i = 0; i < 4; ++i) {
        int rloc = lg + i * 16;
        int node = r0 + rloc;
        float4 acc = make_float4(0.f, 0.f, 0.f, 0.f);
        if (node < N_NODES) {
            F2H sv;
            sv.f = reinterpret_cast<const float2*>(hin + (size_t)node * 64)[cg];
            BNH(sv);
            float2 f0 = __half22float2(sv.h[0]);
            float2 f1 = __half22float2(sv.h[1]);
            acc = make_float4(f0.x * eps1, f0.y * eps1, f1.x * eps1, f1.y * eps1);
            int j0 = row_ptr[node], j1 = row_ptr[node + 1];
            int j = j0;
            for (; j + 8 <= j1; j += 8) {
                int idx[8];
#pragma unroll
                for (int q = 0; q < 8; ++q) idx[q] = csr_src[j + q];
                F2H u[8];
#pragma unroll
                for (int q = 0; q < 8; ++q)
                    u[q].f = reinterpret_cast<const float2*>(hin + (size_t)idx[q] * 64)[cg];
#pragma unroll
                for (int q = 0; q < 8; ++q) {
                    BNH(u[q]);
                    float2 g0 = __half22float2(u[q].h[0]);
                    float2 g1 = __half22float2(u[q].h[1]);
                    acc.x += g0.x; acc.y += g0.y; acc.z += g1.x; acc.w += g1.y;
                }
            }
            for (; j < j1; ++j) {
                F2H u;
                u.f = reinterpret_cast<const float2*>(hin + (size_t)csr_src[j] * 64)[cg];
                BNH(u);
                float2 g0 = __half22float2(u.h[0]);
                float2 g1 = __half22float2(u.h[1]);
                acc.x += g0.x; acc.y += g0.y; acc.z += g1.x; acc.w += g1.y;
            }
        }
        F2H o;
        o.h[0] = __float22half2_rn(make_float2(acc.x, acc.y));
        o.h[1] = __float22half2_rn(make_float2(acc.z, acc.w));
        *reinterpret_cast<float2*>(&xs[rloc][cg * 4]) = o.f;
    }
#undef BNH
    __syncthreads();

    // ---- Phase B: MFMA MLP; wave w owns rows [16w, 16w+16) of xs ----
    int wid = tid >> 6, l = tid & 63;
    int c = l & 15, g = l >> 4;
    int r_base = r0 + wid * 16;

    half4v a1[4];
#pragma unroll
    for (int kk = 0; kk < 4; ++kk)
        a1[kk] = *reinterpret_cast<const half4v*>(&xs[wid * 16 + c][g * 4 + kk * 16]);

    f32x4 acc1[4];
#pragma unroll
    for (int n = 0; n < 4; ++n) {
        const _Float16* bb = wt1 + (size_t)(n * 16 + c) * 64 + g * 4;
        half4v bf[4];
#pragma unroll
        for (int kk = 0; kk < 4; ++kk)
            bf[kk] = *reinterpret_cast<const half4v*>(bb + kk * 16);
        f32x4 z = {0.f, 0.f, 0.f, 0.f};
#pragma unroll
        for (int kk = 0; kk < 4; ++kk)
            z = __builtin_amdgcn_mfma_f32_16x16x16f16(a1[kk], bf[kk], z, 0, 0, 0);
        acc1[n] = z;
    }

    // bias + relu -> h1 transposed into own rows
#pragma unroll
    for (int n = 0; n < 4; ++n) {
        float bj = b1[n * 16 + c];
#pragma unroll
        for (int e = 0; e < 4; ++e) {
            float v = fmaxf(acc1[n][e] + bj, 0.f);
            xs[wid * 16 + g * 4 + e][n * 16 + c] = (_Float16)v;
        }
    }

    half4v a2[4];
#pragma unroll
    for (int kk = 0; kk < 4; ++kk)
        a2[kk] = *reinterpret_cast<const half4v*>(&xs[wid * 16 + c][kk * 16 + g * 4]);

    f32x4 acc2[4];
#pragma unroll
    for (int n = 0; n < 4; ++n) {
        const _Float16* bb = wt2 + (size_t)(n * 16 + c) * 64 + g * 4;
        half4v bf[4];
#pragma unroll
        for (int kk = 0; kk < 4; ++kk)
            bf[kk] = *reinterpret_cast<const half4v*>(bb + kk * 16);
        f32x4 z = {0.f, 0.f, 0.f, 0.f};
#pragma unroll
        for (int kk = 0; kk < 4; ++kk)
            z = __builtin_amdgcn_mfma_f32_16x16x16f16(a2[kk], bf[kk], z, 0, 0, 0);
        acc2[n] = z;
    }

    // bias + relu -> RAW h into own rows + masked BN stats
#pragma unroll
    for (int n = 0; n < 4; ++n) {
        float bj = b2[n * 16 + c];
        float s = 0.f, q = 0.f;
#pragma unroll
        for (int e = 0; e < 4; ++e) {
            float v = fmaxf(acc2[n][e] + bj, 0.f);
            xs[wid * 16 + g * 4 + e][n * 16 + c] = (_Float16)v;
            if (r_base + g * 4 + e < N_NODES) { s += v; q += v * v; }
        }
        atomicAdd(&sred[n * 16 + c], s);
        atomicAdd(&sred[64 + n * 16 + c], q);
    }

    // coalesced store: 2 passes of 8 rows, 8 lanes x 16 B per row
#pragma unroll
    for (int p = 0; p < 2; ++p) {
        int row = p * 8 + (l >> 3);
        int colh = (l & 7) * 8;
        int grow = r_base + row;
        if (grow < N_NODES) {
            float4 v = *reinterpret_cast<const float4*>(&xs[wid * 16 + row][colh]);
            *reinterpret_cast<float4*>(reinterpret_cast<__half*>(hout) +
                                       (size_t)grow * 64 + colh) = v;
        }
    }

    __syncthreads();
    if (tid < 128) atomicAdd(&stats[tid], sred[tid]);
}

// ---------------------------------------------------------------------------
// out[N x 16] = relu(BN3(h)) @ wl + bl   (h raw fp16; BN3 folded on load)
__global__ __launch_bounds__(256) void final_k(const __half* __restrict__ hin,
                                               const float* __restrict__ pstats,
                                               const float* __restrict__ pg,
                                               const float* __restrict__ pbt,
                                               const float* __restrict__ wl,
                                               const float* __restrict__ bl,
                                               float* __restrict__ out) {
    __shared__ float xs[64][68];
    __shared__ float wsh[64 * 16];
    __shared__ float bsh[16];
    __shared__ float ssc[64], sof[64];
    int tid = threadIdx.x;
    int r0 = blockIdx.x * 64;

    if (tid < 64) {
        float mean = pstats[tid] * (1.f / N_NODES);
        float var = pstats[64 + tid] * (1.f / N_NODES) - mean * mean;
        float sc = pg[tid] * rsqrtf(var + BN_EPS);
        ssc[tid] = sc;
        sof[tid] = pbt[tid] - mean * sc;
    }
    reinterpret_cast<float4*>(wsh)[tid] = reinterpret_cast<const float4*>(wl)[tid];
    if (tid < 16) bsh[tid] = bl[tid];
    __syncthreads();

    {
        int rr = tid >> 4, cg = tid & 15;
#pragma unroll
        for (int i = 0; i < 4; ++i) {
            int r = rr + i * 16;
            float4 v = make_float4(0.f, 0.f, 0.f, 0.f);
            if (r0 + r < N_NODES) {
                union { float2 f; __half2 h[2]; } u;
                u.f = reinterpret_cast<const float2*>(hin + (size_t)(r0 + r) * 64)[cg];
                float2 f0 = __half22float2(u.h[0]);
                float2 f1 = __half22float2(u.h[1]);
                int c = cg * 4;
                v.x = fmaxf(fmaf(f0.x, ssc[c + 0], sof[c + 0]), 0.f);
                v.y = fmaxf(fmaf(f0.y, ssc[c + 1], sof[c + 1]), 0.f);
                v.z = fmaxf(fmaf(f1.x, ssc[c + 2], sof[c + 2]), 0.f);
                v.w = fmaxf(fmaf(f1.y, ssc[c + 3], sof[c + 3]), 0.f);
            }
            xs[cg * 4 + 0][r] = v.x;
            xs[cg * 4 + 1][r] = v.y;
            xs[cg * 4 + 2][r] = v.z;
            xs[cg * 4 + 3][r] = v.w;
        }
    }
    __syncthreads();

    int tc = tid & 3, r = tid >> 2;
    int c = tc * 4;
    float acc0 = 0.f, acc1 = 0.f, acc2 = 0.f, acc3 = 0.f;
#pragma unroll 8
    for (int k = 0; k < 64; ++k) {
        float xv = xs[k][r];
        float4 wv = *reinterpret_cast<const float4*>(&wsh[k * 16 + c]);
        acc0 = fmaf(xv, wv.x, acc0);
        acc1 = fmaf(xv, wv.y, acc1);
        acc2 = fmaf(xv, wv.z, acc2);
        acc3 = fmaf(xv, wv.w, acc3);
    }
    int row = r0 + r;
    if (row < N_NODES) {
        float4 o = make_float4(acc0 + bsh[c], acc1 + bsh[c + 1], acc2 + bsh[c + 2], acc3 + bsh[c + 3]);
        *reinterpret_cast<float4*>(out + (size_t)row * 16 + c) = o;
    }
}

// ---------------------------------------------------------------------------
extern "C" void kernel_launch(void* const* d_in, const int* in_sizes, int n_in,
                              void* d_out, int out_size, void* d_ws, size_t ws_size,
                              hipStream_t stream) {
    const float* x = (const float*)d_in[0];
    const int* ei = (const int*)d_in[1];
    const int E = in_sizes[1] / 2;

    const float* eps[3] = {(const float*)d_in[2], (const float*)d_in[9], (const float*)d_in[16]};
    const float* w1[3]  = {(const float*)d_in[3], (const float*)d_in[10], (const float*)d_in[17]};
    const float* b1[3]  = {(const float*)d_in[4], (const float*)d_in[11], (const float*)d_in[18]};
    const float* w2[3]  = {(const float*)d_in[5], (const float*)d_in[12], (const float*)d_in[19]};
    const float* b2[3]  = {(const float*)d_in[6], (const float*)d_in[13], (const float*)d_in[20]};
    const float* g[3]   = {(const float*)d_in[7], (const float*)d_in[14], (const float*)d_in[21]};
    const float* bt[3]  = {(const float*)d_in[8], (const float*)d_in[15], (const float*)d_in[22]};
    const float* wl = (const float*)d_in[23];
    const float* bl = (const float*)d_in[24];

    // workspace layout (fp16 h buffers)
    __half* xh   = (__half*)d_ws;                           // N*64
    __half* ha   = xh + (size_t)N_NODES * 64;
    __half* hb   = ha + (size_t)N_NODES * 64;
    _Float16* wth = (_Float16*)(hb + (size_t)N_NODES * 64); // 6*4096
    float* stats = (float*)(wth + 6 * 4096);
    int* gcnt    = (int*)(stats + 384);
    int* cbase   = gcnt + NC;
    int* gcursor = cbase + (NC + 1);
    int* row_ptr = gcursor + NC;
    int* tail    = row_ptr + (N_NODES + 1);
    size_t used  = (size_t)((char*)tail - (char*)d_ws);

    int* csr_src = tail;                 // E ints, persists through all layers
    int* part;                           // E ints, build-only
    if (used + 2 * (size_t)E * 4 <= ws_size) {
        part = csr_src + E;
    } else {
        part = (int*)d_out;  // consumed by csrD_k before final_k writes d_out
    }

    const int n4 = N_NODES * 16;

    // ---- one-time: CSR build (coarse partition + per-bucket sort) + converts ----
    zero_misc_k<<<2, 256, 0, stream>>>(stats, gcnt);
    tofp16_k<<<(n4 + 255) / 256, 256, 0, stream>>>(x, xh, n4);
    wtr_k<<<6, 256, 0, stream>>>(w1[0], w2[0], w1[1], w2[1], w1[2], w2[2], wth);
    histC_k<<<PART_BLOCKS, 256, 0, stream>>>(ei, gcnt, E);
    scanC_k<<<1, 256, 0, stream>>>(gcnt, cbase, gcursor);
    partC_k<<<PART_BLOCKS, 256, 0, stream>>>(ei, gcursor, part, E);
    csrD_k<<<NC, 256, 0, stream>>>(part, cbase, row_ptr, csr_src);

    // ---- 3 fused GIN layers (BN of prev layer folded into gather) ----
    layer_k<true><<<NBLK64, 256, 0, stream>>>(xh, nullptr, nullptr, nullptr,
                                              row_ptr, csr_src, eps[0],
                                              wth + 0 * 4096, b1[0], wth + 1 * 4096, b2[0],
                                              ha, stats + 0);
    layer_k<false><<<NBLK64, 256, 0, stream>>>(ha, stats + 0, g[0], bt[0],
                                               row_ptr, csr_src, eps[1],
                                               wth + 2 * 4096, b1[1], wth + 3 * 4096, b2[1],
                                               hb, stats + 128);
    layer_k<false><<<NBLK64, 256, 0, stream>>>(hb, stats + 128, g[1], bt[1],
                                               row_ptr, csr_src, eps[2],
                                               wth + 4 * 4096, b1[2], wth + 5 * 4096, b2[2],
                                               ha, stats + 256);

    // ---- final linear with BN3 folded ----
    final_k<<<(N_NODES + 63) / 64, 256, 0, stream>>>(ha, stats + 256, g[2], bt[2],
                                                     wl, bl, (float*)d_out);
}